// Round 10
// baseline (5896.741 us; speedup 1.0000x reference)
//
#include <hip/hip_runtime.h>
#include <stdint.h>

// ---------------------------------------------------------------------------
// Persistent-RNN 2-layer LSTM decoder (B=64,H=1024,OUT=512,SEQ=256), MI355X.
// R10 = R9 (rotating write-once buffers + cached reads + leader aggregation)
//  + scan-first leaders (blocks 224..231, disjoint from FC set)
//  + chunk-granular epochs: fh0 as 4 quarter-words (L1 consumes chunk-by-
//    chunk), fy as 2 half-words (L0 likewise), FC quarter-scans fh1 directly.
//  Detection latency hides under MFMA compute; consumers start on the first
//  quarter while stragglers finish the last.
// ---------------------------------------------------------------------------

#define NBLK 256
#define NTHR 256
#define HDIM 1024
#define ODIM 512
#define BDIM 64
#define SEQL 256
#define LEAD0 224

typedef _Float16 v8h __attribute__((ext_vector_type(8)));
typedef float    v4f __attribute__((ext_vector_type(4)));

// LDS: per k-slice, 64 lanes x 16B contiguous = 1024B (conflict-free b128)
#define WL0_NS 48
#define WL1_NS 64
#define WFC_NS 32
#define WL0_OFF 0
#define WL1_OFF (WL0_NS*1024)
#define WFC_OFF (WL1_OFF + WL1_NS*1024)
#define SMEM_BYTES (WFC_OFF + WFC_NS*1024)   // 147456 B

#define YB_SZ  (BDIM*ODIM*2)            // 64 KB per slot
#define HB_SZ  (BDIM*HDIM*2)            // 128 KB per slot

// flags: fh0[4][256], fh1[4][256], fy[4][32] packed 4B
// epochs: eh0[(wv,f)] 4 words packed 16B (64B line); ey[(wv,f)] 2 words.
#define FH0_REL 0
#define FH1_REL (4*256*4)
#define FY_REL  (FH1_REL + 4*256*4)
#define EH0_REL (FY_REL + 4*32*4)
#define EY_REL  (EH0_REL + 4*8*64)
#define FLG_BYTES (EY_REL + 4*8*64)

__device__ __forceinline__ float fsig(float x)   { return 1.0f / (1.0f + __expf(-x)); }
__device__ __forceinline__ float ftanhf(float x) { return 1.0f - 2.0f / (__expf(2.0f*x) + 1.0f); }

__device__ __forceinline__ unsigned int ald4(const void* p){
  return __hip_atomic_load((const unsigned int*)p, __ATOMIC_RELAXED, __HIP_MEMORY_SCOPE_AGENT);
}
__device__ __forceinline__ void ast4(void* p, unsigned int v){
  __hip_atomic_store((unsigned int*)p, v, __ATOMIC_RELAXED, __HIP_MEMORY_SCOPE_AGENT);
}

// wrap-acquire: once per D steps — drop last-epoch clean L2 lines.
__device__ __forceinline__ void wrap_inv(){
  asm volatile("s_waitcnt vmcnt(0)\n\tbuffer_inv sc1" ::: "memory");
}

// follower: tight poll of one epoch word (uniform address, one txn per round)
__device__ __forceinline__ void wait_word(const unsigned int* w, unsigned int tag){
  while (ald4(w) < tag) {}
  asm volatile("" ::: "memory");
}

// leader: scan a 64-flag quarter (lane ln polls one flag), publish word q
__device__ __forceinline__ void scan_quarter(const unsigned int* rowf, int q,
                                             unsigned int* ew, unsigned int tag){
  const unsigned int* p = rowf + q*64 + (threadIdx.x & 63);
  while (!__all(ald4(p) >= tag)) __builtin_amdgcn_s_sleep(1);
  if ((threadIdx.x & 63) == 0) ast4(ew + q, tag);
  asm volatile("" ::: "memory");
}

// leader: scan a 16-flag y-half (lane ln&15), publish word h
__device__ __forceinline__ void scan_yhalf(const unsigned int* rowf, int h,
                                           unsigned int* ew, unsigned int tag){
  const unsigned int* p = rowf + h*16 + (threadIdx.x & 15);
  while (!__all(ald4(p) >= tag)) __builtin_amdgcn_s_sleep(1);
  if ((threadIdx.x & 63) == 0) ast4(ew + h, tag);
  asm volatile("" ::: "memory");
}

// wave publish: drain this wave's vmem (reads+writes), store tag (1 writer).
__device__ __forceinline__ void publish(unsigned int* flag, unsigned int tag){
  asm volatile("s_waitcnt vmcnt(0)" ::: "memory");
  if ((threadIdx.x & 63) == 0) ast4(flag, tag);
}

// one 256-K-col chunk: 8 cached A loads + 8 MFMAs
__device__ __forceinline__ v4f chunk8(const char* abase, const char* wl, int c, v4f acc){
  v8h A[8];
  #pragma unroll
  for (int j = 0; j < 8; j++) A[j] = *(const v8h*)(abase + (size_t)c*512 + (size_t)j*64);
  #pragma unroll
  for (int j = 0; j < 8; j++){
    v8h B = *(const v8h*)(wl + (size_t)(c*8 + j)*1024);
    acc = __builtin_amdgcn_mfma_f32_16x16x32_f16(A[j], B, acc, 0, 0, 0);
  }
  return acc;
}

// dual chunk: same A feeding two B matrices
__device__ __forceinline__ void chunk8_dual(const char* abase, const char* wlA,
                                            const char* wlB, int c, v4f& a1, v4f& a2){
  v8h A[8];
  #pragma unroll
  for (int j = 0; j < 8; j++) A[j] = *(const v8h*)(abase + (size_t)c*512 + (size_t)j*64);
  #pragma unroll
  for (int j = 0; j < 8; j++){
    v8h BA = *(const v8h*)(wlA + (size_t)(c*8 + j)*1024);
    a1 = __builtin_amdgcn_mfma_f32_16x16x32_f16(A[j], BA, a1, 0, 0, 0);
    v8h BB = *(const v8h*)(wlB + (size_t)(c*8 + j)*1024);
    a2 = __builtin_amdgcn_mfma_f32_16x16x32_f16(A[j], BB, a2, 0, 0, 0);
  }
}

// 4-chunk pipelined gemm (no waits) for p1/prologue
__device__ __forceinline__ v4f gemm4(const char* abase, const char* wl, v4f acc){
  #pragma unroll
  for (int c = 0; c < 4; c++) acc = chunk8(abase, wl, c, acc);
  return acc;
}

// LSTM epilogue: gate gather via xor1/2/3; h packed 4 units -> one 8B sc1 store.
__device__ __forceinline__ void lstm_epi_pack(v4f acc, float bias, float* cs,
                                              char* hbase, int l15, int gidx){
  #pragma unroll
  for (int r = 0; r < 4; r++){
    float v  = acc[r] + bias;
    float x1 = __shfl_xor(v, 1);
    float x2 = __shfl_xor(v, 2);
    float x3 = __shfl_xor(v, 3);
    float vi = (gidx==0)?v :(gidx==1)?x1:(gidx==2)?x2:x3;
    float vf = (gidx==1)?v :(gidx==0)?x1:(gidx==3)?x2:x3;
    float vg = (gidx==2)?v :(gidx==3)?x1:(gidx==0)?x2:x3;
    float vo = (gidx==3)?v :(gidx==2)?x1:(gidx==1)?x2:x3;
    float ii = fsig(vi), ff = fsig(vf), gg = ftanhf(vg), oo = fsig(vo);
    float cn = ff*cs[r] + ii*gg;
    cs[r] = cn;
    float hn = oo * ftanhf(cn);
    unsigned int uv = (unsigned int)__builtin_bit_cast(unsigned short, (_Float16)hn);
    unsigned int o4 = (unsigned int)__shfl_xor((int)uv, 4);
    unsigned int pr = uv | (o4 << 16);
    unsigned int o8 = (unsigned int)__shfl_xor((int)pr, 8);
    if (l15 == 0){
      unsigned long long full = (unsigned long long)pr | ((unsigned long long)o8 << 32);
      __hip_atomic_store((unsigned long long*)(hbase + (size_t)r*(HDIM*2)), full,
                         __ATOMIC_RELAXED, __HIP_MEMORY_SCOPE_AGENT);
    }
  }
}

__global__ void init_kernel(const float* __restrict__ h0,
                            _Float16* __restrict__ h0bi, _Float16* __restrict__ h1bi,
                            _Float16* __restrict__ ybi){
  int i = blockIdx.x*256 + threadIdx.x;
  if (i < BDIM*HDIM){
    h0bi[i] = (_Float16)h0[i];
    h1bi[i] = (_Float16)h0[BDIM*HDIM + i];
  }
  if (i < BDIM*ODIM) ybi[i] = (_Float16)(-2.0f); // SOS
}

__launch_bounds__(NTHR, 1)
__global__ void decoder_kernel(
    const float* __restrict__ Wih0, const float* __restrict__ Whh0,
    const float* __restrict__ bih0, const float* __restrict__ bhh0,
    const float* __restrict__ Wih1, const float* __restrict__ Whh1,
    const float* __restrict__ bih1, const float* __restrict__ bhh1,
    const float* __restrict__ Wfc,  const float* __restrict__ bfc,
    const float* __restrict__ c0in, float* __restrict__ out,
    char* __restrict__ yB, char* __restrict__ h0B, char* __restrict__ h1B,
    char* __restrict__ flg, int dmask)
{
  extern __shared__ char smem[];
  const int bid = blockIdx.x;
  const int tid = threadIdx.x;
  const int wv  = tid >> 6;
  const int ln  = tid & 63;
  const int l15 = ln & 15;
  const int lq  = ln >> 4;
  const int u0  = bid * 4;
  const int f   = bid & 7;                        // follower set / leader id
  const int leader = (bid >= LEAD0 && bid < LEAD0 + 8);

  unsigned int* fh0r = (unsigned int*)(flg + FH0_REL) + wv*256;
  unsigned int* fh1r = (unsigned int*)(flg + FH1_REL) + wv*256;
  unsigned int* fyr  = (unsigned int*)(flg + FY_REL)  + wv*32;
  unsigned int* eh0w = (unsigned int*)(flg + EH0_REL + (wv*8 + f)*64);  // 4 words
  unsigned int* eyw  = (unsigned int*)(flg + EY_REL  + (wv*8 + f)*64);  // 2 words

  // ---- one-time: weights fp32->fp16 into LDS, exact fragment order ----
  for (int slot = tid; slot < WL0_NS*64; slot += NTHR){
    int s = slot >> 6, l = slot & 63;
    int r16 = l & 15, q = l >> 4;
    int grow = (r16 & 3)*HDIM + u0 + (r16 >> 2);
    int kb = s*32 + q*8;
    const float* src; int k0;
    if (kb < ODIM){ src = Wih0 + (size_t)grow*ODIM; k0 = kb; }
    else          { src = Whh0 + (size_t)grow*HDIM; k0 = kb - ODIM; }
    v8h hv;
    #pragma unroll
    for (int j = 0; j < 8; j++) hv[j] = (_Float16)src[k0 + j];
    *(v8h*)(smem + WL0_OFF + s*1024 + l*16) = hv;
  }
  for (int slot = tid; slot < WL1_NS*64; slot += NTHR){
    int s = slot >> 6, l = slot & 63;
    int r16 = l & 15, q = l >> 4;
    int grow = (r16 & 3)*HDIM + u0 + (r16 >> 2);
    int kb = s*32 + q*8;
    const float* src; int k0;
    if (kb < HDIM){ src = Wih1 + (size_t)grow*HDIM; k0 = kb; }
    else          { src = Whh1 + (size_t)grow*HDIM; k0 = kb - HDIM; }
    v8h hv;
    #pragma unroll
    for (int j = 0; j < 8; j++) hv[j] = (_Float16)src[k0 + j];
    *(v8h*)(smem + WL1_OFF + s*1024 + l*16) = hv;
  }
  if (bid < 32){
    for (int slot = tid; slot < WFC_NS*64; slot += NTHR){
      int s = slot >> 6, l = slot & 63;
      int r16 = l & 15, q = l >> 4;
      const float* src = Wfc + (size_t)(bid*16 + r16)*HDIM;
      int k0 = s*32 + q*8;
      v8h hv;
      #pragma unroll
      for (int j = 0; j < 8; j++) hv[j] = (_Float16)src[k0 + j];
      *(v8h*)(smem + WFC_OFF + s*1024 + l*16) = hv;
    }
  }
  __syncthreads();   // LDS weights ready (only barrier in the kernel)

  // ---- per-lane constants ----
  const int gidx = l15 & 3;
  const int unit = u0 + (l15 >> 2);
  const int growL = gidx*HDIM + unit;
  const float bias0 = bih0[growL] + bhh0[growL];
  const float bias1 = bih1[growL] + bhh1[growL];
  float biasf = 0.f;
  if (bid < 32) biasf = bfc[bid*16 + l15];

  const int rb = wv*16 + lq*4;
  float cs0[4], cs1[4];
  #pragma unroll
  for (int r = 0; r < 4; r++){
    int b = rb + r;
    cs0[r] = c0in[(size_t)(0*BDIM + b)*HDIM + unit];
    cs1[r] = c0in[(size_t)(1*BDIM + b)*HDIM + unit];
  }

  const int row = wv*16 + l15;
  const size_t aoffY = (size_t)row*ODIM*2 + (size_t)lq*16;
  const size_t aoffH = (size_t)row*HDIM*2 + (size_t)lq*16;
  const size_t hwoff = ((size_t)rb*HDIM + u0)*2;
  const char* wl0 = smem + WL0_OFF + ln*16;
  const char* wl1 = smem + WL1_OFF + ln*16;
  const char* wlf = smem + WFC_OFF + ln*16;
  const char* wl0r = wl0 + 16*1024;   // Whh0 slices
  const char* wl1r = wl1 + 32*1024;   // Whh1 slices

  // prologue: p0 = Whh0 @ h0_init (slot dmask; init flushed at dispatch end)
  v4f p0 = gemm4(h0B + (size_t)dmask*HB_SZ + aoffH, wl0r, v4f{0.f,0.f,0.f,0.f});

  for (int t = 0; t < SEQL; t++){
    const int sp = (t - 1) & dmask;
    const int sc = t & dmask;

    if ((t & dmask) == 0) wrap_inv();  // once per rotation epoch

    // -- 1: L0 over y[t-1], consumed in 2 halves gated by ey words --
    {
      const char* ybase = yB + (size_t)sp*YB_SZ + aoffY;
      v4f acc = p0;
      #pragma unroll
      for (int h = 0; h < 2; h++){
        if (t > 0){
          if (leader) scan_yhalf(fyr, h, eyw, (unsigned)t);
          else        wait_word(eyw + h, (unsigned)t);
        }
        acc = chunk8(ybase, wl0, h, acc);
      }
      lstm_epi_pack(acc, bias0, cs0, h0B + (size_t)sc*HB_SZ + hwoff, l15, gidx);
    }
    publish(&fh0r[bid], (unsigned)(t+1));

    // -- 2/3: p1 = Whh1@h1[t-1] (off path; visibility via ey>=t chain),
    //         then L1 dual consumed in 4 quarters gated by eh0 words.
    //         Leaders scan FIRST (followers overlap p1 with the scan).
    {
      const char* h1p = h1B + (size_t)sp*HB_SZ + aoffH;
      const char* h0c = h0B + (size_t)sc*HB_SZ + aoffH;
      v4f p1, np0 = {0.f,0.f,0.f,0.f};
      if (leader){
        #pragma unroll
        for (int q = 0; q < 4; q++) scan_quarter(fh0r, q, eh0w, (unsigned)(t+1));
        p1 = gemm4(h1p, wl1r, v4f{0.f,0.f,0.f,0.f});
        #pragma unroll
        for (int q = 0; q < 4; q++) chunk8_dual(h0c, wl1, wl0r, q, p1, np0);
      } else {
        p1 = gemm4(h1p, wl1r, v4f{0.f,0.f,0.f,0.f});
        #pragma unroll
        for (int q = 0; q < 4; q++){
          wait_word(eh0w + q, (unsigned)(t+1));
          chunk8_dual(h0c, wl1, wl0r, q, p1, np0);
        }
      }
      lstm_epi_pack(p1, bias1, cs1, h1B + (size_t)sc*HB_SZ + hwoff, l15, gidx);
      p0 = np0;
    }
    publish(&fh1r[bid], (unsigned)(t+1));

    // -- 4 (blocks 0..31): FC, quarter-scanning fh1 directly --
    if (bid < 32){
      const char* f1 = h1B + (size_t)sc*HB_SZ + aoffH;
      v4f acc = {0.f,0.f,0.f,0.f};
      #pragma unroll
      for (int q = 0; q < 4; q++){
        const unsigned int* pp = fh1r + q*64 + ln;
        while (!__all(ald4(pp) >= (unsigned)(t+1))) __builtin_amdgcn_s_sleep(1);
        asm volatile("" ::: "memory");
        acc = chunk8(f1, wlf, q, acc);
      }
      char* ydst = yB + (size_t)sc*YB_SZ;
      #pragma unroll
      for (int r = 0; r < 4; r++){
        float v = fmaxf(acc[r] + biasf, 0.f);
        int b = rb + r;
        int o = bid*16 + l15;
        out[((size_t)b*SEQL + t)*ODIM + o] = v;
        unsigned int uv = (unsigned int)__builtin_bit_cast(unsigned short, (_Float16)v);
        unsigned int o1 = (unsigned int)__shfl_xor((int)uv, 1);
        unsigned int pr = uv | (o1 << 16);
        unsigned int o2 = (unsigned int)__shfl_xor((int)pr, 2);
        if ((l15 & 3) == 0){
          unsigned long long full = (unsigned long long)pr | ((unsigned long long)o2 << 32);
          __hip_atomic_store((unsigned long long*)(ydst + ((size_t)b*ODIM + o)*2),
                             full, __ATOMIC_RELAXED, __HIP_MEMORY_SCOPE_AGENT);
        }
      }
      publish(&fyr[bid], (unsigned)(t+1));
    }
  }
}

extern "C" void kernel_launch(void* const* d_in, const int* in_sizes, int n_in,
                              void* d_out, int out_size, void* d_ws, size_t ws_size,
                              hipStream_t stream){
  (void)in_sizes; (void)n_in; (void)out_size;

  int D = 16;
  while (D > 2 && (size_t)D*(YB_SZ + 2*HB_SZ) + FLG_BYTES > ws_size) D >>= 1;
  if ((size_t)D*(YB_SZ + 2*HB_SZ) + FLG_BYTES > ws_size) return;

  char* ws  = (char*)d_ws;
  char* yB  = ws;
  char* h0B = yB + (size_t)D*YB_SZ;
  char* h1B = h0B + (size_t)D*HB_SZ;
  char* flg = h1B + (size_t)D*HB_SZ;

  const float* h0   = (const float*)d_in[1];
  const float* c0   = (const float*)d_in[2];
  const float* Wih0 = (const float*)d_in[3];
  const float* Whh0 = (const float*)d_in[4];
  const float* bih0 = (const float*)d_in[5];
  const float* bhh0 = (const float*)d_in[6];
  const float* Wih1 = (const float*)d_in[7];
  const float* Whh1 = (const float*)d_in[8];
  const float* bih1 = (const float*)d_in[9];
  const float* bhh1 = (const float*)d_in[10];
  const float* Wfc  = (const float*)d_in[11];
  const float* bfc  = (const float*)d_in[12];
  float* out = (float*)d_out;

  (void)hipMemsetAsync(flg, 0, FLG_BYTES, stream);
  hipLaunchKernelGGL(init_kernel, dim3(256), dim3(256), 0, stream,
                     h0,
                     (_Float16*)(h0B + (size_t)(D-1)*HB_SZ),
                     (_Float16*)(h1B + (size_t)(D-1)*HB_SZ),
                     (_Float16*)(yB  + (size_t)(D-1)*YB_SZ));

  (void)hipFuncSetAttribute((const void*)decoder_kernel,
                            hipFuncAttributeMaxDynamicSharedMemorySize, SMEM_BYTES);
  hipLaunchKernelGGL(decoder_kernel, dim3(NBLK), dim3(NTHR), SMEM_BYTES, stream,
                     Wih0, Whh0, bih0, bhh0, Wih1, Whh1, bih1, bhh1,
                     Wfc, bfc, c0, out, yB, h0B, h1B, flg, D - 1);
}

// Round 11
// 5753.122 us; speedup vs baseline: 1.0250x; 1.0250x over previous
//
#include <hip/hip_runtime.h>
#include <stdint.h>

// ---------------------------------------------------------------------------
// Persistent-RNN 2-layer LSTM decoder (B=64,H=1024,OUT=512,SEQ=256), MI355X.
// R11 = R9 (rotating write-once buffers + cached reads + leader-aggregated
// store-only flags) + isolated fixes from the R10 post-mortem:
//  * leaders = blocks 224..231 (disjoint from FC set 0..31)
//  * scan-first leaders on the fh0 hop (publish -> scan -> epoch -> p1)
//  * FC publishes fy BEFORE the out[] stores (out off the critical chain)
//  * followers keep s_sleep polls (R10's tight-spin flood reverted)
// No chunk-gating (R10's serialization reverted).
// ---------------------------------------------------------------------------

#define NBLK 256
#define NTHR 256
#define HDIM 1024
#define ODIM 512
#define BDIM 64
#define SEQL 256
#define LEAD0 224

typedef _Float16 v8h __attribute__((ext_vector_type(8)));
typedef float    v4f __attribute__((ext_vector_type(4)));

// LDS: per k-slice, 64 lanes x 16B contiguous = 1024B (conflict-free b128)
#define WL0_NS 48
#define WL1_NS 64
#define WFC_NS 32
#define WL0_OFF 0
#define WL1_OFF (WL0_NS*1024)
#define WFC_OFF (WL1_OFF + WL1_NS*1024)
#define SMEM_BYTES (WFC_OFF + WFC_NS*1024)   // 147456 B

#define YB_SZ  (BDIM*ODIM*2)            // 64 KB per slot
#define HB_SZ  (BDIM*HDIM*2)            // 128 KB per slot

// flags: fh0[4][256], fh1[4][256], fy[4][32] packed 4B
// epochs: eh0[(wv,f)], ey[(wv,f)] one word each, 64B stride.
#define FH0_REL 0
#define FH1_REL (4*256*4)
#define FY_REL  (FH1_REL + 4*256*4)
#define EH0_REL (FY_REL + 4*32*4)
#define EY_REL  (EH0_REL + 4*8*64)
#define FLG_BYTES (EY_REL + 4*8*64)

__device__ __forceinline__ float fsig(float x)   { return 1.0f / (1.0f + __expf(-x)); }
__device__ __forceinline__ float ftanhf(float x) { return 1.0f - 2.0f / (__expf(2.0f*x) + 1.0f); }

__device__ __forceinline__ unsigned long long ald8(const void* p){
  return __hip_atomic_load((const unsigned long long*)p, __ATOMIC_RELAXED, __HIP_MEMORY_SCOPE_AGENT);
}
__device__ __forceinline__ unsigned int ald4(const void* p){
  return __hip_atomic_load((const unsigned int*)p, __ATOMIC_RELAXED, __HIP_MEMORY_SCOPE_AGENT);
}
__device__ __forceinline__ void ast4(void* p, unsigned int v){
  __hip_atomic_store((unsigned int*)p, v, __ATOMIC_RELAXED, __HIP_MEMORY_SCOPE_AGENT);
}

// wrap-acquire: once per D steps — drop last-epoch clean L2 lines.
__device__ __forceinline__ void wrap_inv(){
  asm volatile("s_waitcnt vmcnt(0)\n\tbuffer_inv sc1" ::: "memory");
}

// follower: poll one epoch word with light sleep
__device__ __forceinline__ void wait_word(const unsigned int* w, unsigned int tag){
  while (ald4(w) < tag) __builtin_amdgcn_s_sleep(1);
  asm volatile("" ::: "memory");
}

// leader: scan full 256-flag row (4 flags/lane), then store epoch word
__device__ __forceinline__ void scan256_pub(const unsigned int* rowf, unsigned int* ew,
                                            unsigned int tag){
  const char* p = (const char*)(rowf + (threadIdx.x & 63)*4);
  while (true){
    unsigned long long a = ald8(p);
    unsigned long long b = ald8(p+8);
    unsigned int m0 = (unsigned int)a, m1 = (unsigned int)(a >> 32);
    unsigned int m2 = (unsigned int)b, m3 = (unsigned int)(b >> 32);
    unsigned int m = min(min(m0, m1), min(m2, m3));
    if (__all(m >= tag)) break;
    __builtin_amdgcn_s_sleep(1);
  }
  if ((threadIdx.x & 63) == 0) ast4(ew, tag);
  asm volatile("" ::: "memory");
}

// leader: scan 32-flag y row, then store epoch word
__device__ __forceinline__ void scan32_pub(const unsigned int* rowf, unsigned int* ew,
                                           unsigned int tag){
  const unsigned int* p = rowf + (threadIdx.x & 31);
  while (!__all(ald4(p) >= tag)) __builtin_amdgcn_s_sleep(1);
  if ((threadIdx.x & 63) == 0) ast4(ew, tag);
  asm volatile("" ::: "memory");
}

// direct 256-flag scan (FC blocks' fh1 wait)
__device__ __forceinline__ void wait_grp256(const unsigned int* rowf, unsigned int tag){
  const char* p = (const char*)(rowf + (threadIdx.x & 63)*4);
  while (true){
    unsigned long long a = ald8(p);
    unsigned long long b = ald8(p+8);
    unsigned int m0 = (unsigned int)a, m1 = (unsigned int)(a >> 32);
    unsigned int m2 = (unsigned int)b, m3 = (unsigned int)(b >> 32);
    unsigned int m = min(min(m0, m1), min(m2, m3));
    if (__all(m >= tag)) break;
    __builtin_amdgcn_s_sleep(1);
  }
  asm volatile("" ::: "memory");
}

// wave publish: drain this wave's vmem (reads+writes), store tag (1 writer).
__device__ __forceinline__ void publish(unsigned int* flag, unsigned int tag){
  asm volatile("s_waitcnt vmcnt(0)" ::: "memory");
  if ((threadIdx.x & 63) == 0) ast4(flag, tag);
}

// K-loop: NC chunks of 256 K-cols (8 MFMAs each); A via normal cached loads.
template<int NC>
__device__ __forceinline__ v4f gemm_phase(const char* const cb[], const char* wl, v4f acc){
  v8h A[4][8];
  constexpr int PF = (NC < 3) ? NC : 3;
  #pragma unroll
  for (int p = 0; p < PF; p++){
    #pragma unroll
    for (int j = 0; j < 8; j++) A[p][j] = *(const v8h*)(cb[p] + (size_t)j*64);
  }
  #pragma unroll
  for (int c = 0; c < NC; c++){
    const int cur = c & 3, nx = (c + 3) & 3;
    if (c + 3 < NC){
      #pragma unroll
      for (int j = 0; j < 8; j++) A[nx][j] = *(const v8h*)(cb[c+3] + (size_t)j*64);
    }
    #pragma unroll
    for (int j = 0; j < 8; j++){
      v8h B = *(const v8h*)(wl + (size_t)(c*8 + j)*1024);
      acc = __builtin_amdgcn_mfma_f32_16x16x32_f16(A[cur][j], B, acc, 0, 0, 0);
    }
  }
  return acc;
}

// Same A-stream feeding two B matrices (L1 input-part + next-step L0 recurrent).
__device__ __forceinline__ void gemm_dual4(const char* const cb[], const char* wlA,
                                           const char* wlB, v4f& accA, v4f& accB){
  v8h A[4][8];
  #pragma unroll
  for (int p = 0; p < 3; p++){
    #pragma unroll
    for (int j = 0; j < 8; j++) A[p][j] = *(const v8h*)(cb[p] + (size_t)j*64);
  }
  #pragma unroll
  for (int c = 0; c < 4; c++){
    const int cur = c & 3, nx = (c + 3) & 3;
    if (c + 3 < 4){
      #pragma unroll
      for (int j = 0; j < 8; j++) A[nx][j] = *(const v8h*)(cb[c+3] + (size_t)j*64);
    }
    #pragma unroll
    for (int j = 0; j < 8; j++){
      v8h BA = *(const v8h*)(wlA + (size_t)(c*8 + j)*1024);
      accA = __builtin_amdgcn_mfma_f32_16x16x32_f16(A[cur][j], BA, accA, 0, 0, 0);
      v8h BB = *(const v8h*)(wlB + (size_t)(c*8 + j)*1024);
      accB = __builtin_amdgcn_mfma_f32_16x16x32_f16(A[cur][j], BB, accB, 0, 0, 0);
    }
  }
}

// LSTM epilogue: gate gather via xor1/2/3; h packed 4 units -> one 8B sc1 store.
__device__ __forceinline__ void lstm_epi_pack(v4f acc, float bias, float* cs,
                                              char* hbase, int l15, int gidx){
  #pragma unroll
  for (int r = 0; r < 4; r++){
    float v  = acc[r] + bias;
    float x1 = __shfl_xor(v, 1);
    float x2 = __shfl_xor(v, 2);
    float x3 = __shfl_xor(v, 3);
    float vi = (gidx==0)?v :(gidx==1)?x1:(gidx==2)?x2:x3;
    float vf = (gidx==1)?v :(gidx==0)?x1:(gidx==3)?x2:x3;
    float vg = (gidx==2)?v :(gidx==3)?x1:(gidx==0)?x2:x3;
    float vo = (gidx==3)?v :(gidx==2)?x1:(gidx==1)?x2:x3;
    float ii = fsig(vi), ff = fsig(vf), gg = ftanhf(vg), oo = fsig(vo);
    float cn = ff*cs[r] + ii*gg;
    cs[r] = cn;
    float hn = oo * ftanhf(cn);
    unsigned int uv = (unsigned int)__builtin_bit_cast(unsigned short, (_Float16)hn);
    unsigned int o4 = (unsigned int)__shfl_xor((int)uv, 4);
    unsigned int pr = uv | (o4 << 16);
    unsigned int o8 = (unsigned int)__shfl_xor((int)pr, 8);
    if (l15 == 0){
      unsigned long long full = (unsigned long long)pr | ((unsigned long long)o8 << 32);
      __hip_atomic_store((unsigned long long*)(hbase + (size_t)r*(HDIM*2)), full,
                         __ATOMIC_RELAXED, __HIP_MEMORY_SCOPE_AGENT);
    }
  }
}

__global__ void init_kernel(const float* __restrict__ h0,
                            _Float16* __restrict__ h0bi, _Float16* __restrict__ h1bi,
                            _Float16* __restrict__ ybi){
  int i = blockIdx.x*256 + threadIdx.x;
  if (i < BDIM*HDIM){
    h0bi[i] = (_Float16)h0[i];
    h1bi[i] = (_Float16)h0[BDIM*HDIM + i];
  }
  if (i < BDIM*ODIM) ybi[i] = (_Float16)(-2.0f); // SOS
}

__launch_bounds__(NTHR, 1)
__global__ void decoder_kernel(
    const float* __restrict__ Wih0, const float* __restrict__ Whh0,
    const float* __restrict__ bih0, const float* __restrict__ bhh0,
    const float* __restrict__ Wih1, const float* __restrict__ Whh1,
    const float* __restrict__ bih1, const float* __restrict__ bhh1,
    const float* __restrict__ Wfc,  const float* __restrict__ bfc,
    const float* __restrict__ c0in, float* __restrict__ out,
    char* __restrict__ yB, char* __restrict__ h0B, char* __restrict__ h1B,
    char* __restrict__ flg, int dmask)
{
  extern __shared__ char smem[];
  const int bid = blockIdx.x;
  const int tid = threadIdx.x;
  const int wv  = tid >> 6;
  const int ln  = tid & 63;
  const int l15 = ln & 15;
  const int lq  = ln >> 4;
  const int u0  = bid * 4;
  const int f   = bid & 7;
  const int leader = (bid >= LEAD0 && bid < LEAD0 + 8);

  unsigned int* fh0r = (unsigned int*)(flg + FH0_REL) + wv*256;
  unsigned int* fh1r = (unsigned int*)(flg + FH1_REL) + wv*256;
  unsigned int* fyr  = (unsigned int*)(flg + FY_REL)  + wv*32;
  unsigned int* eh0  = (unsigned int*)(flg + EH0_REL + (wv*8 + f)*64);
  unsigned int* ey   = (unsigned int*)(flg + EY_REL  + (wv*8 + f)*64);

  // ---- one-time: weights fp32->fp16 into LDS, exact fragment order ----
  for (int slot = tid; slot < WL0_NS*64; slot += NTHR){
    int s = slot >> 6, l = slot & 63;
    int r16 = l & 15, q = l >> 4;
    int grow = (r16 & 3)*HDIM + u0 + (r16 >> 2);
    int kb = s*32 + q*8;
    const float* src; int k0;
    if (kb < ODIM){ src = Wih0 + (size_t)grow*ODIM; k0 = kb; }
    else          { src = Whh0 + (size_t)grow*HDIM; k0 = kb - ODIM; }
    v8h hv;
    #pragma unroll
    for (int j = 0; j < 8; j++) hv[j] = (_Float16)src[k0 + j];
    *(v8h*)(smem + WL0_OFF + s*1024 + l*16) = hv;
  }
  for (int slot = tid; slot < WL1_NS*64; slot += NTHR){
    int s = slot >> 6, l = slot & 63;
    int r16 = l & 15, q = l >> 4;
    int grow = (r16 & 3)*HDIM + u0 + (r16 >> 2);
    int kb = s*32 + q*8;
    const float* src; int k0;
    if (kb < HDIM){ src = Wih1 + (size_t)grow*HDIM; k0 = kb; }
    else          { src = Whh1 + (size_t)grow*HDIM; k0 = kb - HDIM; }
    v8h hv;
    #pragma unroll
    for (int j = 0; j < 8; j++) hv[j] = (_Float16)src[k0 + j];
    *(v8h*)(smem + WL1_OFF + s*1024 + l*16) = hv;
  }
  if (bid < 32){
    for (int slot = tid; slot < WFC_NS*64; slot += NTHR){
      int s = slot >> 6, l = slot & 63;
      int r16 = l & 15, q = l >> 4;
      const float* src = Wfc + (size_t)(bid*16 + r16)*HDIM;
      int k0 = s*32 + q*8;
      v8h hv;
      #pragma unroll
      for (int j = 0; j < 8; j++) hv[j] = (_Float16)src[k0 + j];
      *(v8h*)(smem + WFC_OFF + s*1024 + l*16) = hv;
    }
  }
  __syncthreads();   // LDS weights ready (only barrier in the kernel)

  // ---- per-lane constants ----
  const int gidx = l15 & 3;
  const int unit = u0 + (l15 >> 2);
  const int growL = gidx*HDIM + unit;
  const float bias0 = bih0[growL] + bhh0[growL];
  const float bias1 = bih1[growL] + bhh1[growL];
  float biasf = 0.f;
  if (bid < 32) biasf = bfc[bid*16 + l15];

  const int rb = wv*16 + lq*4;
  float cs0[4], cs1[4];
  #pragma unroll
  for (int r = 0; r < 4; r++){
    int b = rb + r;
    cs0[r] = c0in[(size_t)(0*BDIM + b)*HDIM + unit];
    cs1[r] = c0in[(size_t)(1*BDIM + b)*HDIM + unit];
  }

  const int row = wv*16 + l15;
  const size_t aoffY = (size_t)row*ODIM*2 + (size_t)lq*16;
  const size_t aoffH = (size_t)row*HDIM*2 + (size_t)lq*16;
  const size_t hwoff = ((size_t)rb*HDIM + u0)*2;
  const char* wl0 = smem + WL0_OFF + ln*16;
  const char* wl1 = smem + WL1_OFF + ln*16;
  const char* wlf = smem + WFC_OFF + ln*16;
  const char* wl0r = wl0 + 16*1024;   // Whh0 slices
  const char* wl1r = wl1 + 32*1024;   // Whh1 slices

  // prologue: p0 = Whh0 @ h0_init
  v4f p0 = {0.f,0.f,0.f,0.f};
  {
    const char* hi = h0B + (size_t)dmask*HB_SZ + aoffH;
    const char* cb[4] = { hi, hi+512, hi+1024, hi+1536 };
    p0 = gemm_phase<4>(cb, wl0r, p0);
  }

  for (int t = 0; t < SEQL; t++){
    const int sp = (t - 1) & dmask;
    const int sc = t & dmask;

    if ((t & dmask) == 0) wrap_inv();  // once per rotation epoch

    // -- 1: y[t-1] ready? (leaders 224..231 scan; followers poll epoch word)
    if (t > 0){
      if (leader) scan32_pub(fyr, ey, (unsigned)t);
      else        wait_word(ey, (unsigned)t);
    }

    // -- 2: L0 input part (K=512) + recurrent partial -> h0[t]
    {
      const char* ysrc = yB + (size_t)sp*YB_SZ + aoffY;
      const char* cb[2] = { ysrc, ysrc+512 };
      v4f acc = gemm_phase<2>(cb, wl0, p0);
      lstm_epi_pack(acc, bias0, cs0, h0B + (size_t)sc*HB_SZ + hwoff, l15, gidx);
    }
    publish(&fh0r[bid], (unsigned)(t+1));

    // -- 3: leader scans fh0 FIRST (epoch out ASAP), then computes p1;
    //       followers compute p1 (overlapping the scan), then poll epoch.
    v4f p1 = {0.f,0.f,0.f,0.f};
    {
      const char* hs = h1B + (size_t)sp*HB_SZ + aoffH;
      const char* cb[4] = { hs, hs+512, hs+1024, hs+1536 };
      if (leader){
        scan256_pub(fh0r, eh0, (unsigned)(t+1));
        p1 = gemm_phase<4>(cb, wl1r, p1);
      } else {
        p1 = gemm_phase<4>(cb, wl1r, p1);
        wait_word(eh0, (unsigned)(t+1));
      }
    }

    // -- 4: L1 input part + fused next-step L0 recurrent (shared A) -> h1[t]
    {
      const char* hs = h0B + (size_t)sc*HB_SZ + aoffH;
      const char* cb[4] = { hs, hs+512, hs+1024, hs+1536 };
      v4f np0 = {0.f,0.f,0.f,0.f};
      gemm_dual4(cb, wl1, wl0r, p1, np0);
      lstm_epi_pack(p1, bias1, cs1, h1B + (size_t)sc*HB_SZ + hwoff, l15, gidx);
      p0 = np0;
    }
    publish(&fh1r[bid], (unsigned)(t+1));

    // -- 5 (blocks 0..31): FC -> y[t] (publish fy BEFORE out stores)
    if (bid < 32){
      wait_grp256(fh1r, (unsigned)(t+1));
      const char* f1 = h1B + (size_t)sc*HB_SZ + aoffH;
      const char* cb[4] = { f1, f1+512, f1+1024, f1+1536 };
      v4f acc = {0.f,0.f,0.f,0.f};
      acc = gemm_phase<4>(cb, wlf, acc);
      char* ydst = yB + (size_t)sc*YB_SZ;
      float yv[4];
      #pragma unroll
      for (int r = 0; r < 4; r++){
        float v = fmaxf(acc[r] + biasf, 0.f);
        yv[r] = v;
        unsigned int uv = (unsigned int)__builtin_bit_cast(unsigned short, (_Float16)v);
        unsigned int o1 = (unsigned int)__shfl_xor((int)uv, 1);
        unsigned int pr = uv | (o1 << 16);
        unsigned int o2 = (unsigned int)__shfl_xor((int)pr, 2);
        if ((l15 & 3) == 0){
          int b = rb + r;
          int o = bid*16 + l15;
          unsigned long long full = (unsigned long long)pr | ((unsigned long long)o2 << 32);
          __hip_atomic_store((unsigned long long*)(ydst + ((size_t)b*ODIM + o)*2),
                             full, __ATOMIC_RELAXED, __HIP_MEMORY_SCOPE_AGENT);
        }
      }
      publish(&fyr[bid], (unsigned)(t+1));
      // out stores AFTER the publish (drained by the next step's publish)
      #pragma unroll
      for (int r = 0; r < 4; r++){
        int b = rb + r;
        int o = bid*16 + l15;
        out[((size_t)b*SEQL + t)*ODIM + o] = yv[r];
      }
    }
  }
}

extern "C" void kernel_launch(void* const* d_in, const int* in_sizes, int n_in,
                              void* d_out, int out_size, void* d_ws, size_t ws_size,
                              hipStream_t stream){
  (void)in_sizes; (void)n_in; (void)out_size;

  int D = 16;
  while (D > 2 && (size_t)D*(YB_SZ + 2*HB_SZ) + FLG_BYTES > ws_size) D >>= 1;
  if ((size_t)D*(YB_SZ + 2*HB_SZ) + FLG_BYTES > ws_size) return;

  char* ws  = (char*)d_ws;
  char* yB  = ws;
  char* h0B = yB + (size_t)D*YB_SZ;
  char* h1B = h0B + (size_t)D*HB_SZ;
  char* flg = h1B + (size_t)D*HB_SZ;

  const float* h0   = (const float*)d_in[1];
  const float* c0   = (const float*)d_in[2];
  const float* Wih0 = (const float*)d_in[3];
  const float* Whh0 = (const float*)d_in[4];
  const float* bih0 = (const float*)d_in[5];
  const float* bhh0 = (const float*)d_in[6];
  const float* Wih1 = (const float*)d_in[7];
  const float* Whh1 = (const float*)d_in[8];
  const float* bih1 = (const float*)d_in[9];
  const float* bhh1 = (const float*)d_in[10];
  const float* Wfc  = (const float*)d_in[11];
  const float* bfc  = (const float*)d_in[12];
  float* out = (float*)d_out;

  (void)hipMemsetAsync(flg, 0, FLG_BYTES, stream);
  hipLaunchKernelGGL(init_kernel, dim3(256), dim3(256), 0, stream,
                     h0,
                     (_Float16*)(h0B + (size_t)(D-1)*HB_SZ),
                     (_Float16*)(h1B + (size_t)(D-1)*HB_SZ),
                     (_Float16*)(yB  + (size_t)(D-1)*YB_SZ));

  (void)hipFuncSetAttribute((const void*)decoder_kernel,
                            hipFuncAttributeMaxDynamicSharedMemorySize, SMEM_BYTES);
  hipLaunchKernelGGL(decoder_kernel, dim3(NBLK), dim3(NTHR), SMEM_BYTES, stream,
                     Wih0, Whh0, bih0, bhh0, Wih1, Whh1, bih1, bhh1,
                     Wfc, bfc, c0, out, yB, h0B, h1B, flg, D - 1);
}

// Round 12
// 4919.767 us; speedup vs baseline: 1.1986x; 1.1694x over previous
//
#include <hip/hip_runtime.h>
#include <stdint.h>

// ---------------------------------------------------------------------------
// Persistent-RNN 2-layer LSTM decoder (B=64,H=1024,OUT=512,SEQ=256), MI355X.
// R12 = R9 (rotating write-once buffers + cached reads + leader-aggregated
// store-only flags) with SYMMETRIC hops:
//  * FC distributed: every block computes 2 of 512 output dims (K=1024,
//    no redundancy). Removes the 32-block relay choke inside hop 3.
//  * fy becomes a standard 256-producer flag row.
//  * three disjoint leader octets: eh0 <- blocks 0..7, eh1 <- 8..15,
//    ey <- 16..23 (no block leads more than one hop).
// R9 orderings otherwise preserved (p1-then-scan on the fh0 hop).
// ---------------------------------------------------------------------------

#define NBLK 256
#define NTHR 256
#define HDIM 1024
#define ODIM 512
#define BDIM 64
#define SEQL 256

typedef _Float16 v8h __attribute__((ext_vector_type(8)));
typedef float    v4f __attribute__((ext_vector_type(4)));

// LDS: per k-slice, 64 lanes x 16B contiguous = 1024B (conflict-free b128)
#define WL0_NS 48
#define WL1_NS 64
#define WFC_NS 32
#define WL0_OFF 0
#define WL1_OFF (WL0_NS*1024)
#define WFC_OFF (WL1_OFF + WL1_NS*1024)
#define SMEM_BYTES (WFC_OFF + WFC_NS*1024)   // 147456 B

#define YB_SZ  (BDIM*ODIM*2)            // 64 KB per slot
#define HB_SZ  (BDIM*HDIM*2)            // 128 KB per slot

// flags: fh0[4][256], fh1[4][256], fy[4][256] packed 4B
// epochs: eh0/eh1/ey [(wv,f)] one word each, 64B stride.
#define FH0_REL 0
#define FH1_REL (4*256*4)
#define FY_REL  (FH1_REL + 4*256*4)
#define EH0_REL (FY_REL + 4*256*4)
#define EH1_REL (EH0_REL + 4*8*64)
#define EY_REL  (EH1_REL + 4*8*64)
#define FLG_BYTES (EY_REL + 4*8*64)

__device__ __forceinline__ float fsig(float x)   { return 1.0f / (1.0f + __expf(-x)); }
__device__ __forceinline__ float ftanhf(float x) { return 1.0f - 2.0f / (__expf(2.0f*x) + 1.0f); }

__device__ __forceinline__ unsigned long long ald8(const void* p){
  return __hip_atomic_load((const unsigned long long*)p, __ATOMIC_RELAXED, __HIP_MEMORY_SCOPE_AGENT);
}
__device__ __forceinline__ unsigned int ald4(const void* p){
  return __hip_atomic_load((const unsigned int*)p, __ATOMIC_RELAXED, __HIP_MEMORY_SCOPE_AGENT);
}
__device__ __forceinline__ void ast4(void* p, unsigned int v){
  __hip_atomic_store((unsigned int*)p, v, __ATOMIC_RELAXED, __HIP_MEMORY_SCOPE_AGENT);
}

// wrap-acquire: once per D steps — drop last-epoch clean L2 lines.
__device__ __forceinline__ void wrap_inv(){
  asm volatile("s_waitcnt vmcnt(0)\n\tbuffer_inv sc1" ::: "memory");
}

// follower: poll one epoch word with light sleep
__device__ __forceinline__ void wait_word(const unsigned int* w, unsigned int tag){
  while (ald4(w) < tag) __builtin_amdgcn_s_sleep(1);
  asm volatile("" ::: "memory");
}

// leader: scan full 256-flag row (4 flags/lane), then store epoch word
__device__ __forceinline__ void scan256_pub(const unsigned int* rowf, unsigned int* ew,
                                            unsigned int tag){
  const char* p = (const char*)(rowf + (threadIdx.x & 63)*4);
  while (true){
    unsigned long long a = ald8(p);
    unsigned long long b = ald8(p+8);
    unsigned int m0 = (unsigned int)a, m1 = (unsigned int)(a >> 32);
    unsigned int m2 = (unsigned int)b, m3 = (unsigned int)(b >> 32);
    unsigned int m = min(min(m0, m1), min(m2, m3));
    if (__all(m >= tag)) break;
    __builtin_amdgcn_s_sleep(1);
  }
  if ((threadIdx.x & 63) == 0) ast4(ew, tag);
  asm volatile("" ::: "memory");
}

// wave publish: drain this wave's vmem (reads+writes), store tag (1 writer).
__device__ __forceinline__ void publish(unsigned int* flag, unsigned int tag){
  asm volatile("s_waitcnt vmcnt(0)" ::: "memory");
  if ((threadIdx.x & 63) == 0) ast4(flag, tag);
}

// K-loop: NC chunks of 256 K-cols (8 MFMAs each); A via normal cached loads.
template<int NC>
__device__ __forceinline__ v4f gemm_phase(const char* const cb[], const char* wl, v4f acc){
  v8h A[4][8];
  constexpr int PF = (NC < 3) ? NC : 3;
  #pragma unroll
  for (int p = 0; p < PF; p++){
    #pragma unroll
    for (int j = 0; j < 8; j++) A[p][j] = *(const v8h*)(cb[p] + (size_t)j*64);
  }
  #pragma unroll
  for (int c = 0; c < NC; c++){
    const int cur = c & 3, nx = (c + 3) & 3;
    if (c + 3 < NC){
      #pragma unroll
      for (int j = 0; j < 8; j++) A[nx][j] = *(const v8h*)(cb[c+3] + (size_t)j*64);
    }
    #pragma unroll
    for (int j = 0; j < 8; j++){
      v8h B = *(const v8h*)(wl + (size_t)(c*8 + j)*1024);
      acc = __builtin_amdgcn_mfma_f32_16x16x32_f16(A[cur][j], B, acc, 0, 0, 0);
    }
  }
  return acc;
}

// Same A-stream feeding two B matrices (L1 input-part + next-step L0 recurrent).
__device__ __forceinline__ void gemm_dual4(const char* const cb[], const char* wlA,
                                           const char* wlB, v4f& accA, v4f& accB){
  v8h A[4][8];
  #pragma unroll
  for (int p = 0; p < 3; p++){
    #pragma unroll
    for (int j = 0; j < 8; j++) A[p][j] = *(const v8h*)(cb[p] + (size_t)j*64);
  }
  #pragma unroll
  for (int c = 0; c < 4; c++){
    const int cur = c & 3, nx = (c + 3) & 3;
    if (c + 3 < 4){
      #pragma unroll
      for (int j = 0; j < 8; j++) A[nx][j] = *(const v8h*)(cb[c+3] + (size_t)j*64);
    }
    #pragma unroll
    for (int j = 0; j < 8; j++){
      v8h BA = *(const v8h*)(wlA + (size_t)(c*8 + j)*1024);
      accA = __builtin_amdgcn_mfma_f32_16x16x32_f16(A[cur][j], BA, accA, 0, 0, 0);
      v8h BB = *(const v8h*)(wlB + (size_t)(c*8 + j)*1024);
      accB = __builtin_amdgcn_mfma_f32_16x16x32_f16(A[cur][j], BB, accB, 0, 0, 0);
    }
  }
}

// LSTM epilogue: gate gather via xor1/2/3; h packed 4 units -> one 8B sc1 store.
__device__ __forceinline__ void lstm_epi_pack(v4f acc, float bias, float* cs,
                                              char* hbase, int l15, int gidx){
  #pragma unroll
  for (int r = 0; r < 4; r++){
    float v  = acc[r] + bias;
    float x1 = __shfl_xor(v, 1);
    float x2 = __shfl_xor(v, 2);
    float x3 = __shfl_xor(v, 3);
    float vi = (gidx==0)?v :(gidx==1)?x1:(gidx==2)?x2:x3;
    float vf = (gidx==1)?v :(gidx==0)?x1:(gidx==3)?x2:x3;
    float vg = (gidx==2)?v :(gidx==3)?x1:(gidx==0)?x2:x3;
    float vo = (gidx==3)?v :(gidx==2)?x1:(gidx==1)?x2:x3;
    float ii = fsig(vi), ff = fsig(vf), gg = ftanhf(vg), oo = fsig(vo);
    float cn = ff*cs[r] + ii*gg;
    cs[r] = cn;
    float hn = oo * ftanhf(cn);
    unsigned int uv = (unsigned int)__builtin_bit_cast(unsigned short, (_Float16)hn);
    unsigned int o4 = (unsigned int)__shfl_xor((int)uv, 4);
    unsigned int pr = uv | (o4 << 16);
    unsigned int o8 = (unsigned int)__shfl_xor((int)pr, 8);
    if (l15 == 0){
      unsigned long long full = (unsigned long long)pr | ((unsigned long long)o8 << 32);
      __hip_atomic_store((unsigned long long*)(hbase + (size_t)r*(HDIM*2)), full,
                         __ATOMIC_RELAXED, __HIP_MEMORY_SCOPE_AGENT);
    }
  }
}

__global__ void init_kernel(const float* __restrict__ h0,
                            _Float16* __restrict__ h0bi, _Float16* __restrict__ h1bi,
                            _Float16* __restrict__ ybi){
  int i = blockIdx.x*256 + threadIdx.x;
  if (i < BDIM*HDIM){
    h0bi[i] = (_Float16)h0[i];
    h1bi[i] = (_Float16)h0[BDIM*HDIM + i];
  }
  if (i < BDIM*ODIM) ybi[i] = (_Float16)(-2.0f); // SOS
}

__launch_bounds__(NTHR, 1)
__global__ void decoder_kernel(
    const float* __restrict__ Wih0, const float* __restrict__ Whh0,
    const float* __restrict__ bih0, const float* __restrict__ bhh0,
    const float* __restrict__ Wih1, const float* __restrict__ Whh1,
    const float* __restrict__ bih1, const float* __restrict__ bhh1,
    const float* __restrict__ Wfc,  const float* __restrict__ bfc,
    const float* __restrict__ c0in, float* __restrict__ out,
    char* __restrict__ yB, char* __restrict__ h0B, char* __restrict__ h1B,
    char* __restrict__ flg, int dmask)
{
  extern __shared__ char smem[];
  const int bid = blockIdx.x;
  const int tid = threadIdx.x;
  const int wv  = tid >> 6;
  const int ln  = tid & 63;
  const int l15 = ln & 15;
  const int lq  = ln >> 4;
  const int u0  = bid * 4;
  const int f   = bid & 7;
  const int lead_h0 = (bid < 8);
  const int lead_h1 = (bid >= 8  && bid < 16);
  const int lead_y  = (bid >= 16 && bid < 24);

  unsigned int* fh0r = (unsigned int*)(flg + FH0_REL) + wv*256;
  unsigned int* fh1r = (unsigned int*)(flg + FH1_REL) + wv*256;
  unsigned int* fyr  = (unsigned int*)(flg + FY_REL)  + wv*256;
  unsigned int* eh0  = (unsigned int*)(flg + EH0_REL + (wv*8 + f)*64);
  unsigned int* eh1  = (unsigned int*)(flg + EH1_REL + (wv*8 + f)*64);
  unsigned int* ey   = (unsigned int*)(flg + EY_REL  + (wv*8 + f)*64);

  // ---- one-time: weights fp32->fp16 into LDS, exact fragment order ----
  for (int slot = tid; slot < WL0_NS*64; slot += NTHR){
    int s = slot >> 6, l = slot & 63;
    int r16 = l & 15, q = l >> 4;
    int grow = (r16 & 3)*HDIM + u0 + (r16 >> 2);
    int kb = s*32 + q*8;
    const float* src; int k0;
    if (kb < ODIM){ src = Wih0 + (size_t)grow*ODIM; k0 = kb; }
    else          { src = Whh0 + (size_t)grow*HDIM; k0 = kb - ODIM; }
    v8h hv;
    #pragma unroll
    for (int j = 0; j < 8; j++) hv[j] = (_Float16)src[k0 + j];
    *(v8h*)(smem + WL0_OFF + s*1024 + l*16) = hv;
  }
  for (int slot = tid; slot < WL1_NS*64; slot += NTHR){
    int s = slot >> 6, l = slot & 63;
    int r16 = l & 15, q = l >> 4;
    int grow = (r16 & 3)*HDIM + u0 + (r16 >> 2);
    int kb = s*32 + q*8;
    const float* src; int k0;
    if (kb < HDIM){ src = Wih1 + (size_t)grow*HDIM; k0 = kb; }
    else          { src = Whh1 + (size_t)grow*HDIM; k0 = kb - HDIM; }
    v8h hv;
    #pragma unroll
    for (int j = 0; j < 8; j++) hv[j] = (_Float16)src[k0 + j];
    *(v8h*)(smem + WL1_OFF + s*1024 + l*16) = hv;
  }
  // FC tile: rows 0..1 = dims 2*bid, 2*bid+1; rows 2..15 zero (all blocks)
  for (int slot = tid; slot < WFC_NS*64; slot += NTHR){
    int s = slot >> 6, l = slot & 63;
    int r16 = l & 15, q = l >> 4;
    int k0 = s*32 + q*8;
    v8h hv;
    if (r16 < 2){
      const float* src = Wfc + (size_t)(bid*2 + r16)*HDIM;
      #pragma unroll
      for (int j = 0; j < 8; j++) hv[j] = (_Float16)src[k0 + j];
    } else {
      #pragma unroll
      for (int j = 0; j < 8; j++) hv[j] = (_Float16)0.0f;
    }
    *(v8h*)(smem + WFC_OFF + s*1024 + l*16) = hv;
  }
  __syncthreads();   // LDS weights ready (only barrier in the kernel)

  // ---- per-lane constants ----
  const int gidx = l15 & 3;
  const int unit = u0 + (l15 >> 2);
  const int growL = gidx*HDIM + unit;
  const float bias0 = bih0[growL] + bhh0[growL];
  const float bias1 = bih1[growL] + bhh1[growL];
  const float biasf = (l15 < 2) ? bfc[bid*2 + l15] : 0.f;

  const int rb = wv*16 + lq*4;
  float cs0[4], cs1[4];
  #pragma unroll
  for (int r = 0; r < 4; r++){
    int b = rb + r;
    cs0[r] = c0in[(size_t)(0*BDIM + b)*HDIM + unit];
    cs1[r] = c0in[(size_t)(1*BDIM + b)*HDIM + unit];
  }

  const int row = wv*16 + l15;
  const size_t aoffY = (size_t)row*ODIM*2 + (size_t)lq*16;
  const size_t aoffH = (size_t)row*HDIM*2 + (size_t)lq*16;
  const size_t hwoff = ((size_t)rb*HDIM + u0)*2;
  const char* wl0 = smem + WL0_OFF + ln*16;
  const char* wl1 = smem + WL1_OFF + ln*16;
  const char* wlf = smem + WFC_OFF + ln*16;
  const char* wl0r = wl0 + 16*1024;   // Whh0 slices
  const char* wl1r = wl1 + 32*1024;   // Whh1 slices

  // prologue: p0 = Whh0 @ h0_init
  v4f p0 = {0.f,0.f,0.f,0.f};
  {
    const char* hi = h0B + (size_t)dmask*HB_SZ + aoffH;
    const char* cb[4] = { hi, hi+512, hi+1024, hi+1536 };
    p0 = gemm_phase<4>(cb, wl0r, p0);
  }

  for (int t = 0; t < SEQL; t++){
    const int sp = (t - 1) & dmask;
    const int sc = t & dmask;

    if ((t & dmask) == 0) wrap_inv();  // once per rotation epoch

    // -- hop3 tail: y[t-1] ready? (leaders 16..23 scan fy; others poll ey)
    if (t > 0){
      if (lead_y) scan256_pub(fyr, ey, (unsigned)t);
      else        wait_word(ey, (unsigned)t);
    }

    // -- L0 input part (K=512) + recurrent partial -> h0[t]
    {
      const char* ysrc = yB + (size_t)sp*YB_SZ + aoffY;
      const char* cb[2] = { ysrc, ysrc+512 };
      v4f acc = gemm_phase<2>(cb, wl0, p0);
      lstm_epi_pack(acc, bias0, cs0, h0B + (size_t)sc*HB_SZ + hwoff, l15, gidx);
    }
    publish(&fh0r[bid], (unsigned)(t+1));

    // -- p1 = Whh1 @ h1[t-1] (off critical path), then hop1: fh0 rendezvous
    v4f p1 = {0.f,0.f,0.f,0.f};
    {
      const char* hs = h1B + (size_t)sp*HB_SZ + aoffH;
      const char* cb[4] = { hs, hs+512, hs+1024, hs+1536 };
      p1 = gemm_phase<4>(cb, wl1r, p1);
      if (lead_h0) scan256_pub(fh0r, eh0, (unsigned)(t+1));
      else         wait_word(eh0, (unsigned)(t+1));
    }

    // -- L1 input part + fused next-step L0 recurrent (shared A) -> h1[t]
    {
      const char* hs = h0B + (size_t)sc*HB_SZ + aoffH;
      const char* cb[4] = { hs, hs+512, hs+1024, hs+1536 };
      v4f np0 = {0.f,0.f,0.f,0.f};
      gemm_dual4(cb, wl1, wl0r, p1, np0);
      lstm_epi_pack(p1, bias1, cs1, h1B + (size_t)sc*HB_SZ + hwoff, l15, gidx);
      p0 = np0;
    }
    publish(&fh1r[bid], (unsigned)(t+1));

    // -- hop2: fh1 rendezvous (leaders 8..15 scan; others poll eh1)
    if (lead_h1) scan256_pub(fh1r, eh1, (unsigned)(t+1));
    else         wait_word(eh1, (unsigned)(t+1));

    // -- FC (all blocks, 2 dims each): y[t] cols 2*bid..2*bid+1
    {
      const char* f1 = h1B + (size_t)sc*HB_SZ + aoffH;
      const char* cb[4] = { f1, f1+512, f1+1024, f1+1536 };
      v4f acc = {0.f,0.f,0.f,0.f};
      acc = gemm_phase<4>(cb, wlf, acc);
      char* ydst = yB + (size_t)sc*YB_SZ;
      #pragma unroll
      for (int r = 0; r < 4; r++){
        float v = fmaxf(acc[r] + biasf, 0.f);
        int b = rb + r;
        // y fp16 pair store (dims 2*bid, 2*bid+1) by l15==0 lanes
        unsigned int uv = (unsigned int)__builtin_bit_cast(unsigned short, (_Float16)v);
        unsigned int o1 = (unsigned int)__shfl_xor((int)uv, 1);
        if (l15 == 0){
          unsigned int pr = uv | (o1 << 16);
          ast4(ydst + ((size_t)b*ODIM + bid*2)*2, pr);
        }
        // out float store (2 lanes per row)
        if (l15 < 2) out[((size_t)b*SEQL + t)*ODIM + bid*2 + l15] = v;
      }
    }
    publish(&fyr[bid], (unsigned)(t+1));
  }
}

extern "C" void kernel_launch(void* const* d_in, const int* in_sizes, int n_in,
                              void* d_out, int out_size, void* d_ws, size_t ws_size,
                              hipStream_t stream){
  (void)in_sizes; (void)n_in; (void)out_size;

  int D = 16;
  while (D > 2 && (size_t)D*(YB_SZ + 2*HB_SZ) + FLG_BYTES > ws_size) D >>= 1;
  if ((size_t)D*(YB_SZ + 2*HB_SZ) + FLG_BYTES > ws_size) return;

  char* ws  = (char*)d_ws;
  char* yB  = ws;
  char* h0B = yB + (size_t)D*YB_SZ;
  char* h1B = h0B + (size_t)D*HB_SZ;
  char* flg = h1B + (size_t)D*HB_SZ;

  const float* h0   = (const float*)d_in[1];
  const float* c0   = (const float*)d_in[2];
  const float* Wih0 = (const float*)d_in[3];
  const float* Whh0 = (const float*)d_in[4];
  const float* bih0 = (const float*)d_in[5];
  const float* bhh0 = (const float*)d_in[6];
  const float* Wih1 = (const float*)d_in[7];
  const float* Whh1 = (const float*)d_in[8];
  const float* bih1 = (const float*)d_in[9];
  const float* bhh1 = (const float*)d_in[10];
  const float* Wfc  = (const float*)d_in[11];
  const float* bfc  = (const float*)d_in[12];
  float* out = (float*)d_out;

  (void)hipMemsetAsync(flg, 0, FLG_BYTES, stream);
  hipLaunchKernelGGL(init_kernel, dim3(256), dim3(256), 0, stream,
                     h0,
                     (_Float16*)(h0B + (size_t)(D-1)*HB_SZ),
                     (_Float16*)(h1B + (size_t)(D-1)*HB_SZ),
                     (_Float16*)(yB  + (size_t)(D-1)*YB_SZ));

  (void)hipFuncSetAttribute((const void*)decoder_kernel,
                            hipFuncAttributeMaxDynamicSharedMemorySize, SMEM_BYTES);
  hipLaunchKernelGGL(decoder_kernel, dim3(NBLK), dim3(NTHR), SMEM_BYTES, stream,
                     Wih0, Whh0, bih0, bhh0, Wih1, Whh1, bih1, bhh1,
                     Wfc, bfc, c0, out, yB, h0B, h1B, flg, D - 1);
}